// Round 6
// baseline (440.025 us; speedup 1.0000x reference)
//
#include <hip/hip_runtime.h>

#define B_ 512
#define S_ 512
#define E_ 128
#define H_ 100
#define T_ 64
#define BS_ (B_*S_)

typedef __attribute__((ext_vector_type(8))) short bf16x8;
typedef __attribute__((ext_vector_type(4))) float f32x4;
union U16x4 { uint4 u; bf16x8 s; };

__device__ __forceinline__ unsigned f2bf1(float x){
    unsigned u = __float_as_uint(x);
    return (u + 0x7FFFu + ((u>>16)&1u)) >> 16;
}
__device__ __forceinline__ float bf2f(unsigned short h){
    return __uint_as_float(((unsigned)h)<<16);
}
__device__ __forceinline__ float rfl_f(float x){
    return __uint_as_float(__builtin_amdgcn_readfirstlane(__float_as_uint(x)));
}

// ---------------------------------------------------------------------------
// Prep: W1/W2 bf16 MFMA B-fragment images (k-map: k=(lane>>4)*8+i).
// ---------------------------------------------------------------------------
__global__ void prep_kernel(const float* __restrict__ W1, const float* __restrict__ W2,
                            uint4* __restrict__ W1f, uint4* __restrict__ W2f)
{
    const int tid = threadIdx.x;
    for (int idx = tid; idx < 7*4*64; idx += 256) {
        int lane = idx & 63, kt = (idx>>6)&3, nt = idx>>8;
        int n = nt*16 + (lane&15);
        int kb = kt*32 + (lane>>4)*8;
        unsigned wv[4];
        #pragma unroll
        for (int p = 0; p < 4; ++p) {
            float v0 = (n < H_) ? W1[(kb+2*p  )*H_ + n] : 0.f;
            float v1 = (n < H_) ? W1[(kb+2*p+1)*H_ + n] : 0.f;
            wv[p] = f2bf1(v0) | (f2bf1(v1) << 16);
        }
        W1f[idx] = make_uint4(wv[0],wv[1],wv[2],wv[3]);
    }
    for (int idx = tid; idx < 4*4*64; idx += 256) {
        int lane = idx & 63, kt = (idx>>6)&3, nt = idx>>8;
        int n = nt*16 + (lane&15);
        int kb = kt*32 + (lane>>4)*8;
        unsigned wv[4];
        #pragma unroll
        for (int p = 0; p < 4; ++p) {
            int k0 = kb+2*p, k1 = kb+2*p+1;
            float v0 = (k0 < H_) ? W2[k0*T_ + n] : 0.f;
            float v1 = (k1 < H_) ? W2[k1*T_ + n] : 0.f;
            wv[p] = f2bf1(v0) | (f2bf1(v1) << 16);
        }
        W2f[idx] = make_uint4(wv[0],wv[1],wv[2],wv[3]);
    }
}

// ---------------------------------------------------------------------------
// MLP (unchanged — clean A/B; counters become visible once crf drops).
// ---------------------------------------------------------------------------
__global__ __launch_bounds__(256, 4) void mlp_kernel(
    const int* __restrict__ inputs, const float* __restrict__ tbl,
    const float* __restrict__ b1, const float* __restrict__ b2,
    const uint4* __restrict__ W1f, const uint4* __restrict__ W2f,
    unsigned short* __restrict__ em)
{
    __shared__ uint4 sA2[1024];    // 16 KB; per-wave A2 frag staging

    const int tid  = threadIdx.x;
    const int lane = tid & 63;
    const int w    = tid >> 6;
    const int col  = lane & 15;
    const int hi   = lane >> 4;
    const int rowin = hi * 4;      // C/D: col=lane&15, row=(lane>>4)*4+reg (m89)

    const int rg = blockIdx.x*64 + w*16 + col;
    const int i0 = inputs[rg*3+0], i1 = inputs[rg*3+1], i2 = inputs[rg*3+2];
    const float4* r0 = (const float4*)tbl + (size_t)i0*(E_/4);
    const float4* r1 = (const float4*)tbl + (size_t)i1*(E_/4);
    const float4* r2 = (const float4*)tbl + (size_t)i2*(E_/4);

    U16x4 a[4];
    #pragma unroll
    for (int kt = 0; kt < 4; ++kt) {
        int fo = kt*8 + hi*2;
        float4 x0 = r0[fo], y0 = r0[fo+1];
        float4 x1 = r1[fo], y1 = r1[fo+1];
        float4 x2 = r2[fo], y2 = r2[fo+1];
        float v0 = x0.x+x1.x+x2.x, v1 = x0.y+x1.y+x2.y;
        float v2 = x0.z+x1.z+x2.z, v3 = x0.w+x1.w+x2.w;
        float v4 = y0.x+y1.x+y2.x, v5 = y0.y+y1.y+y2.y;
        float v6 = y0.z+y1.z+y2.z, v7 = y0.w+y1.w+y2.w;
        a[kt].u = make_uint4(f2bf1(v0)|(f2bf1(v1)<<16), f2bf1(v2)|(f2bf1(v3)<<16),
                             f2bf1(v4)|(f2bf1(v5)<<16), f2bf1(v6)|(f2bf1(v7)<<16));
    }

    f32x4 acc1[7];
    #pragma unroll
    for (int nt = 0; nt < 7; ++nt) {
        int n = nt*16 + col;
        float bv = (n < H_) ? b1[n] : 0.f;
        f32x4 c; c[0]=bv; c[1]=bv; c[2]=bv; c[3]=bv;
        #pragma unroll
        for (int k = 0; k < 4; ++k) {
            U16x4 bfr; bfr.u = W1f[(nt*4+k)*64 + lane];
            c = __builtin_amdgcn_mfma_f32_16x16x32_bf16(a[k].s, bfr.s, c, 0,0,0);
        }
        acc1[nt] = c;
    }
    #pragma unroll
    for (int nt = 0; nt < 7; ++nt)
        #pragma unroll
        for (int rr = 0; rr < 4; ++rr) {
            float x = acc1[nt][rr];
            acc1[nt][rr] = 1.f - 2.f/(__expf(2.f*x)+1.f);
        }

    if (lane >= 32) sA2[(w*4+3)*64 + lane] = make_uint4(0,0,0,0);
    unsigned short* A2h = (unsigned short*)sA2;
    #pragma unroll
    for (int nt = 0; nt < 7; ++nt)
        #pragma unroll
        for (int rr = 0; rr < 4; ++rr) {
            int k2 = nt*16 + col;
            int kt2 = k2 >> 5, g2 = (k2>>3)&3, i2v = k2&7;
            int u4idx = (w*4 + kt2)*64 + g2*16 + (rowin + rr);
            A2h[u4idx*8 + i2v] = (unsigned short)f2bf1(acc1[nt][rr]);
        }
    __builtin_amdgcn_wave_barrier();

    U16x4 a2[4];
    #pragma unroll
    for (int k = 0; k < 4; ++k) a2[k].u = sA2[(w*4+k)*64 + lane];
    #pragma unroll
    for (int nt2 = 0; nt2 < 4; ++nt2) {
        float bv = b2[nt2*16 + col];
        f32x4 c; c[0]=bv; c[1]=bv; c[2]=bv; c[3]=bv;
        #pragma unroll
        for (int k = 0; k < 4; ++k) {
            U16x4 bfr; bfr.u = W2f[(nt2*4+k)*64 + lane];
            c = __builtin_amdgcn_mfma_f32_16x16x32_bf16(a2[k].s, bfr.s, c, 0,0,0);
        }
        #pragma unroll
        for (int rr = 0; rr < 4; ++rr) {
            size_t row = (size_t)(blockIdx.x*64 + w*16 + rowin + rr);
            em[row*T_ + nt2*16 + col] = (unsigned short)f2bf1(c[rr]);
        }
    }
}

// ---------------------------------------------------------------------------
// CRF scan, linear space, SGPR-broadcast matvec (round-5 structure) with the
// register-allocation fix: __launch_bounds__(64, 1) releases the full VGPR
// budget so Ecol[64] stays RESIDENT (round 5: VGPR_Count=60 -> Ecol spilled
// to scratch -> 64 scratch loads on the chain; that was the regression).
// ---------------------------------------------------------------------------
__global__ __launch_bounds__(64, 1) void crf_kernel(
    const int* __restrict__ inputs, const int* __restrict__ tags,
    const unsigned short* __restrict__ em, const float* __restrict__ start_trans,
    const float* __restrict__ end_trans, const float* __restrict__ trans,
    float* __restrict__ out)
{
    __shared__ unsigned short sem[2][8*T_];   // 2 x 1 KB em staging (off-chain)

    const int b = blockIdx.x;
    const int j = threadIdx.x;
    const unsigned short* em_b = em + (size_t)b*S_*T_;
    const int* tags_b = tags + b*S_;
    const int* in_b = inputs + (size_t)b*S_*3;

    // mask ballots + numerator
    unsigned long long mball[8];
    float partial = 0.f;
    #pragma unroll
    for (int g = 0; g < 8; ++g) {
        int t = g*64 + j;
        int a0 = in_b[t*3+0], a1 = in_b[t*3+1], a2 = in_b[t*3+2];
        bool mk = ((a0 | a1 | a2) != 0);
        mball[g] = __ballot(mk);
        if (t >= 1 && mk) {
            int tp = tags_b[t-1], tc = tags_b[t];
            partial += trans[tp*T_ + tc] + bf2f(em_b[(size_t)t*T_ + tc]);
        }
    }
    int mcount = 0;
    #pragma unroll
    for (int g = 0; g < 8; ++g) mcount += __popcll(mball[g]);
    mball[0] &= ~1ull;
    #pragma unroll
    for (int off = 32; off >= 1; off >>= 1) partial += __shfl_xor(partial, off, 64);
    const int tag0 = tags_b[0];
    int se = mcount - 1; if (se < 0) se = 0;
    const int last_tag = tags_b[se];
    const float numer = partial + start_trans[tag0] + bf2f(em_b[tag0]) + end_trans[last_tag];

    // E column j (constant over scan) — must stay in VGPRs
    float Ecol[64];
    #pragma unroll
    for (int i = 0; i < 64; ++i) Ecol[i] = __expf(trans[i*T_ + j]);

    // init: a = exp(alpha0 - m), ls = m
    float x0v = start_trans[j] + bf2f(em_b[j]);
    float ls = rfl_f(x0v);
    float a = __expf(x0v - ls);

    // group staging (off-chain): sem[g&1] holds group g; eg[] = exp(em)
    const uint4* em4 = (const uint4*)em_b;
    uint4 gbuf = em4[j];
    ((uint4*)sem[0])[j] = gbuf;
    __builtin_amdgcn_wave_barrier();
    float eg[8];
    #pragma unroll
    for (int c = 0; c < 8; ++c) eg[c] = __expf(bf2f(sem[0][c*T_ + j]));
    gbuf = em4[64 + j];

    for (int g = 0; g < 64; ++g) {
        unsigned short raw16[8];
        if (g < 63) {
            ((uint4*)sem[(g+1)&1])[j] = gbuf;
            __builtin_amdgcn_wave_barrier();
            #pragma unroll
            for (int c = 0; c < 8; ++c) raw16[c] = sem[(g+1)&1][c*T_ + j];
            if (g < 62) gbuf = em4[(g+2)*64 + j];
        }
        const unsigned mg = (unsigned)((mball[g>>3] >> ((g&7)*8)) & 0xFFull);

        #pragma unroll
        for (int c = 0; c < 8; ++c) {
            // off-chain scale prep (overlaps matvec issue)
            float s    = rfl_f(a);
            float sinv = __builtin_amdgcn_rcpf(s);
            float logs = __logf(s);
            float keep = a * sinv;
            float emulc = eg[c] * sinv;

            // SGPR-broadcast matvec: 64 readlane + 64 fmac, fully unrolled,
            // constant lane indices, 8 parallel accumulators.
            float acc8[8] = {0.f,0.f,0.f,0.f,0.f,0.f,0.f,0.f};
            unsigned au = __float_as_uint(a);
            #pragma unroll
            for (int hi = 0; hi < 8; ++hi) {
                #pragma unroll
                for (int lo = 0; lo < 8; ++lo) {
                    const int i = hi*8 + lo;
                    float sa = __uint_as_float(__builtin_amdgcn_readlane(au, i));
                    acc8[lo] = fmaf(sa, Ecol[i], acc8[lo]);
                }
            }
            float y = ((acc8[0]+acc8[1])+(acc8[2]+acc8[3]))
                    + ((acc8[4]+acc8[5])+(acc8[6]+acc8[7]));

            float cand = y * emulc;
            a = ((mg >> c) & 1u) ? cand : keep;
            ls += logs;
        }
        if (g < 63) {
            #pragma unroll
            for (int c = 0; c < 8; ++c) eg[c] = __expf(bf2f(raw16[c]));
        }
    }

    // denominator = ls + log(sum_j a_j * exp(end_j))
    float x = a * __expf(end_trans[j]);
    #pragma unroll
    for (int off = 32; off >= 1; off >>= 1) x += __shfl_xor(x, off, 64);
    if (j == 0) out[b] = ls + __logf(x) - numer;
}

// ---------------------------------------------------------------------------
extern "C" void kernel_launch(void* const* d_in, const int* in_sizes, int n_in,
                              void* d_out, int out_size, void* d_ws, size_t ws_size,
                              hipStream_t stream) {
    const int*   inputs      = (const int*)  d_in[0];
    const int*   tags        = (const int*)  d_in[1];
    const float* emb_table   = (const float*)d_in[2];
    const float* W1          = (const float*)d_in[3];
    const float* b1          = (const float*)d_in[4];
    const float* W2          = (const float*)d_in[5];
    const float* b2          = (const float*)d_in[6];
    const float* start_trans = (const float*)d_in[7];
    const float* end_trans   = (const float*)d_in[8];
    const float* transitions = (const float*)d_in[9];
    float* out = (float*)d_out;

    unsigned short* em = (unsigned short*)d_ws;            // 32 MiB bf16
    uint4* W1f = (uint4*)((char*)d_ws + (size_t)BS_*T_*2);
    uint4* W2f = W1f + 7*4*64;

    prep_kernel<<<dim3(1), dim3(256), 0, stream>>>(W1, W2, W1f, W2f);
    mlp_kernel<<<dim3(BS_/64), dim3(256), 0, stream>>>(
        inputs, emb_table, b1, b2, W1f, W2f, em);
    crf_kernel<<<dim3(B_), dim3(64), 0, stream>>>(
        inputs, tags, em, start_trans, end_trans, transitions, out);
}

// Round 7
// 438.438 us; speedup vs baseline: 1.0036x; 1.0036x over previous
//
#include <hip/hip_runtime.h>

#define B_ 512
#define S_ 512
#define E_ 128
#define H_ 100
#define T_ 64
#define BS_ (B_*S_)

typedef __attribute__((ext_vector_type(8))) short bf16x8;
typedef __attribute__((ext_vector_type(4))) float f32x4;
union U16x4 { uint4 u; bf16x8 s; };

__device__ __forceinline__ unsigned f2bf1(float x){
    unsigned u = __float_as_uint(x);
    return (u + 0x7FFFu + ((u>>16)&1u)) >> 16;
}
__device__ __forceinline__ float bf2f(unsigned short h){
    return __uint_as_float(((unsigned)h)<<16);
}
__device__ __forceinline__ float rfl_f(float x){
    return __uint_as_float(__builtin_amdgcn_readfirstlane(__float_as_uint(x)));
}

// ---------------------------------------------------------------------------
// Prep: W1/W2 bf16 MFMA B-fragment images (k-map: k=(lane>>4)*8+i).
// ---------------------------------------------------------------------------
__global__ void prep_kernel(const float* __restrict__ W1, const float* __restrict__ W2,
                            uint4* __restrict__ W1f, uint4* __restrict__ W2f)
{
    const int tid = threadIdx.x;
    for (int idx = tid; idx < 7*4*64; idx += 256) {
        int lane = idx & 63, kt = (idx>>6)&3, nt = idx>>8;
        int n = nt*16 + (lane&15);
        int kb = kt*32 + (lane>>4)*8;
        unsigned wv[4];
        #pragma unroll
        for (int p = 0; p < 4; ++p) {
            float v0 = (n < H_) ? W1[(kb+2*p  )*H_ + n] : 0.f;
            float v1 = (n < H_) ? W1[(kb+2*p+1)*H_ + n] : 0.f;
            wv[p] = f2bf1(v0) | (f2bf1(v1) << 16);
        }
        W1f[idx] = make_uint4(wv[0],wv[1],wv[2],wv[3]);
    }
    for (int idx = tid; idx < 4*4*64; idx += 256) {
        int lane = idx & 63, kt = (idx>>6)&3, nt = idx>>8;
        int n = nt*16 + (lane&15);
        int kb = kt*32 + (lane>>4)*8;
        unsigned wv[4];
        #pragma unroll
        for (int p = 0; p < 4; ++p) {
            int k0 = kb+2*p, k1 = kb+2*p+1;
            float v0 = (k0 < H_) ? W2[k0*T_ + n] : 0.f;
            float v1 = (k1 < H_) ? W2[k1*T_ + n] : 0.f;
            wv[p] = f2bf1(v0) | (f2bf1(v1) << 16);
        }
        W2f[idx] = make_uint4(wv[0],wv[1],wv[2],wv[3]);
    }
}

// ---------------------------------------------------------------------------
// MLP (unchanged — clean A/B; counters become visible once crf drops).
// ---------------------------------------------------------------------------
__global__ __launch_bounds__(256, 4) void mlp_kernel(
    const int* __restrict__ inputs, const float* __restrict__ tbl,
    const float* __restrict__ b1, const float* __restrict__ b2,
    const uint4* __restrict__ W1f, const uint4* __restrict__ W2f,
    unsigned short* __restrict__ em)
{
    __shared__ uint4 sA2[1024];    // 16 KB; per-wave A2 frag staging

    const int tid  = threadIdx.x;
    const int lane = tid & 63;
    const int w    = tid >> 6;
    const int col  = lane & 15;
    const int hi   = lane >> 4;
    const int rowin = hi * 4;      // C/D: col=lane&15, row=(lane>>4)*4+reg (m89)

    const int rg = blockIdx.x*64 + w*16 + col;
    const int i0 = inputs[rg*3+0], i1 = inputs[rg*3+1], i2 = inputs[rg*3+2];
    const float4* r0 = (const float4*)tbl + (size_t)i0*(E_/4);
    const float4* r1 = (const float4*)tbl + (size_t)i1*(E_/4);
    const float4* r2 = (const float4*)tbl + (size_t)i2*(E_/4);

    U16x4 a[4];
    #pragma unroll
    for (int kt = 0; kt < 4; ++kt) {
        int fo = kt*8 + hi*2;
        float4 x0 = r0[fo], y0 = r0[fo+1];
        float4 x1 = r1[fo], y1 = r1[fo+1];
        float4 x2 = r2[fo], y2 = r2[fo+1];
        float v0 = x0.x+x1.x+x2.x, v1 = x0.y+x1.y+x2.y;
        float v2 = x0.z+x1.z+x2.z, v3 = x0.w+x1.w+x2.w;
        float v4 = y0.x+y1.x+y2.x, v5 = y0.y+y1.y+y2.y;
        float v6 = y0.z+y1.z+y2.z, v7 = y0.w+y1.w+y2.w;
        a[kt].u = make_uint4(f2bf1(v0)|(f2bf1(v1)<<16), f2bf1(v2)|(f2bf1(v3)<<16),
                             f2bf1(v4)|(f2bf1(v5)<<16), f2bf1(v6)|(f2bf1(v7)<<16));
    }

    f32x4 acc1[7];
    #pragma unroll
    for (int nt = 0; nt < 7; ++nt) {
        int n = nt*16 + col;
        float bv = (n < H_) ? b1[n] : 0.f;
        f32x4 c; c[0]=bv; c[1]=bv; c[2]=bv; c[3]=bv;
        #pragma unroll
        for (int k = 0; k < 4; ++k) {
            U16x4 bfr; bfr.u = W1f[(nt*4+k)*64 + lane];
            c = __builtin_amdgcn_mfma_f32_16x16x32_bf16(a[k].s, bfr.s, c, 0,0,0);
        }
        acc1[nt] = c;
    }
    #pragma unroll
    for (int nt = 0; nt < 7; ++nt)
        #pragma unroll
        for (int rr = 0; rr < 4; ++rr) {
            float x = acc1[nt][rr];
            acc1[nt][rr] = 1.f - 2.f/(__expf(2.f*x)+1.f);
        }

    if (lane >= 32) sA2[(w*4+3)*64 + lane] = make_uint4(0,0,0,0);
    unsigned short* A2h = (unsigned short*)sA2;
    #pragma unroll
    for (int nt = 0; nt < 7; ++nt)
        #pragma unroll
        for (int rr = 0; rr < 4; ++rr) {
            int k2 = nt*16 + col;
            int kt2 = k2 >> 5, g2 = (k2>>3)&3, i2v = k2&7;
            int u4idx = (w*4 + kt2)*64 + g2*16 + (rowin + rr);
            A2h[u4idx*8 + i2v] = (unsigned short)f2bf1(acc1[nt][rr]);
        }
    __builtin_amdgcn_wave_barrier();

    U16x4 a2[4];
    #pragma unroll
    for (int k = 0; k < 4; ++k) a2[k].u = sA2[(w*4+k)*64 + lane];
    #pragma unroll
    for (int nt2 = 0; nt2 < 4; ++nt2) {
        float bv = b2[nt2*16 + col];
        f32x4 c; c[0]=bv; c[1]=bv; c[2]=bv; c[3]=bv;
        #pragma unroll
        for (int k = 0; k < 4; ++k) {
            U16x4 bfr; bfr.u = W2f[(nt2*4+k)*64 + lane];
            c = __builtin_amdgcn_mfma_f32_16x16x32_bf16(a2[k].s, bfr.s, c, 0,0,0);
        }
        #pragma unroll
        for (int rr = 0; rr < 4; ++rr) {
            size_t row = (size_t)(blockIdx.x*64 + w*16 + rowin + rr);
            em[row*T_ + nt2*16 + col] = (unsigned short)f2bf1(c[rr]);
        }
    }
}

// ---------------------------------------------------------------------------
// CRF scan, linear space, SGPR-broadcast matvec.
// ROUND 7 FIX: __launch_bounds__'s 2nd arg only sets the *min* of
// amdgpu-waves-per-eu — allocator still targeted default occupancy and kept
// Ecol[64] in scratch (VGPR_Count=60 in r5 AND r6, dur identical).
// amdgpu_waves_per_eu(1,1) pins the range -> full 512-VGPR budget ->
// Ecol resident. Occupancy is irrelevant here (512 waves on 1024 SIMDs).
// ---------------------------------------------------------------------------
__global__ __launch_bounds__(64)
__attribute__((amdgpu_waves_per_eu(1, 1)))
void crf_kernel(
    const int* __restrict__ inputs, const int* __restrict__ tags,
    const unsigned short* __restrict__ em, const float* __restrict__ start_trans,
    const float* __restrict__ end_trans, const float* __restrict__ trans,
    float* __restrict__ out)
{
    __shared__ unsigned short sem[2][8*T_];   // 2 x 1 KB em staging (off-chain)

    const int b = blockIdx.x;
    const int j = threadIdx.x;
    const unsigned short* em_b = em + (size_t)b*S_*T_;
    const int* tags_b = tags + b*S_;
    const int* in_b = inputs + (size_t)b*S_*3;

    // mask ballots + numerator
    unsigned long long mball[8];
    float partial = 0.f;
    #pragma unroll
    for (int g = 0; g < 8; ++g) {
        int t = g*64 + j;
        int a0 = in_b[t*3+0], a1 = in_b[t*3+1], a2 = in_b[t*3+2];
        bool mk = ((a0 | a1 | a2) != 0);
        mball[g] = __ballot(mk);
        if (t >= 1 && mk) {
            int tp = tags_b[t-1], tc = tags_b[t];
            partial += trans[tp*T_ + tc] + bf2f(em_b[(size_t)t*T_ + tc]);
        }
    }
    int mcount = 0;
    #pragma unroll
    for (int g = 0; g < 8; ++g) mcount += __popcll(mball[g]);
    mball[0] &= ~1ull;
    #pragma unroll
    for (int off = 32; off >= 1; off >>= 1) partial += __shfl_xor(partial, off, 64);
    const int tag0 = tags_b[0];
    int se = mcount - 1; if (se < 0) se = 0;
    const int last_tag = tags_b[se];
    const float numer = partial + start_trans[tag0] + bf2f(em_b[tag0]) + end_trans[last_tag];

    // E column j (constant over scan) — must stay in VGPRs
    float Ecol[64];
    #pragma unroll
    for (int i = 0; i < 64; ++i) Ecol[i] = __expf(trans[i*T_ + j]);

    // init: a = exp(alpha0 - m), ls = m
    float x0v = start_trans[j] + bf2f(em_b[j]);
    float ls = rfl_f(x0v);
    float a = __expf(x0v - ls);

    // group staging (off-chain): sem[g&1] holds group g; eg[] = exp(em)
    const uint4* em4 = (const uint4*)em_b;
    uint4 gbuf = em4[j];
    ((uint4*)sem[0])[j] = gbuf;
    __builtin_amdgcn_wave_barrier();
    float eg[8];
    #pragma unroll
    for (int c = 0; c < 8; ++c) eg[c] = __expf(bf2f(sem[0][c*T_ + j]));
    gbuf = em4[64 + j];

    for (int g = 0; g < 64; ++g) {
        unsigned short raw16[8];
        if (g < 63) {
            ((uint4*)sem[(g+1)&1])[j] = gbuf;
            __builtin_amdgcn_wave_barrier();
            #pragma unroll
            for (int c = 0; c < 8; ++c) raw16[c] = sem[(g+1)&1][c*T_ + j];
            if (g < 62) gbuf = em4[(g+2)*64 + j];
        }
        const unsigned mg = (unsigned)((mball[g>>3] >> ((g&7)*8)) & 0xFFull);

        #pragma unroll
        for (int c = 0; c < 8; ++c) {
            // off-chain scale prep (overlaps matvec issue)
            float s    = rfl_f(a);
            float sinv = __builtin_amdgcn_rcpf(s);
            float logs = __logf(s);
            float keep = a * sinv;
            float emulc = eg[c] * sinv;

            // SGPR-broadcast matvec: 64 readlane + 64 fmac, fully unrolled,
            // constant lane indices, 8 parallel accumulators.
            float acc8[8] = {0.f,0.f,0.f,0.f,0.f,0.f,0.f,0.f};
            unsigned au = __float_as_uint(a);
            #pragma unroll
            for (int hi = 0; hi < 8; ++hi) {
                #pragma unroll
                for (int lo = 0; lo < 8; ++lo) {
                    const int i = hi*8 + lo;
                    float sa = __uint_as_float(__builtin_amdgcn_readlane(au, i));
                    acc8[lo] = fmaf(sa, Ecol[i], acc8[lo]);
                }
            }
            float y = ((acc8[0]+acc8[1])+(acc8[2]+acc8[3]))
                    + ((acc8[4]+acc8[5])+(acc8[6]+acc8[7]));

            float cand = y * emulc;
            a = ((mg >> c) & 1u) ? cand : keep;
            ls += logs;
        }
        if (g < 63) {
            #pragma unroll
            for (int c = 0; c < 8; ++c) eg[c] = __expf(bf2f(raw16[c]));
        }
    }

    // denominator = ls + log(sum_j a_j * exp(end_j))
    float x = a * __expf(end_trans[j]);
    #pragma unroll
    for (int off = 32; off >= 1; off >>= 1) x += __shfl_xor(x, off, 64);
    if (j == 0) out[b] = ls + __logf(x) - numer;
}

// ---------------------------------------------------------------------------
extern "C" void kernel_launch(void* const* d_in, const int* in_sizes, int n_in,
                              void* d_out, int out_size, void* d_ws, size_t ws_size,
                              hipStream_t stream) {
    const int*   inputs      = (const int*)  d_in[0];
    const int*   tags        = (const int*)  d_in[1];
    const float* emb_table   = (const float*)d_in[2];
    const float* W1          = (const float*)d_in[3];
    const float* b1          = (const float*)d_in[4];
    const float* W2          = (const float*)d_in[5];
    const float* b2          = (const float*)d_in[6];
    const float* start_trans = (const float*)d_in[7];
    const float* end_trans   = (const float*)d_in[8];
    const float* transitions = (const float*)d_in[9];
    float* out = (float*)d_out;

    unsigned short* em = (unsigned short*)d_ws;            // 32 MiB bf16
    uint4* W1f = (uint4*)((char*)d_ws + (size_t)BS_*T_*2);
    uint4* W2f = W1f + 7*4*64;

    prep_kernel<<<dim3(1), dim3(256), 0, stream>>>(W1, W2, W1f, W2f);
    mlp_kernel<<<dim3(BS_/64), dim3(256), 0, stream>>>(
        inputs, emb_table, b1, b2, W1f, W2f, em);
    crf_kernel<<<dim3(B_), dim3(64), 0, stream>>>(
        inputs, tags, em, start_trans, end_trans, transitions, out);
}

// Round 8
// 334.945 us; speedup vs baseline: 1.3137x; 1.3090x over previous
//
#include <hip/hip_runtime.h>

#define B_ 512
#define S_ 512
#define E_ 128
#define H_ 100
#define T_ 64
#define BS_ (B_*S_)

typedef __attribute__((ext_vector_type(8))) short bf16x8;
typedef __attribute__((ext_vector_type(4))) float f32x4;
typedef __attribute__((ext_vector_type(2))) float f32x2;
union U16x4 { uint4 u; bf16x8 s; };

__device__ __forceinline__ unsigned f2bf1(float x){
    unsigned u = __float_as_uint(x);
    return (u + 0x7FFFu + ((u>>16)&1u)) >> 16;
}
__device__ __forceinline__ float bf2f(unsigned short h){
    return __uint_as_float(((unsigned)h)<<16);
}
__device__ __forceinline__ float rfl_f(float x){
    return __uint_as_float(__builtin_amdgcn_readfirstlane(__float_as_uint(x)));
}

// ---------------------------------------------------------------------------
// Prep: W1/W2 bf16 MFMA B-fragment images. ROUND 8: parallelized across 44
// blocks (was 1 block serial on one CU — suspected 30-50 us).
// ---------------------------------------------------------------------------
__global__ __launch_bounds__(64) void prep_kernel(
    const float* __restrict__ W1, const float* __restrict__ W2,
    uint4* __restrict__ W1f, uint4* __restrict__ W2f)
{
    const int idx = blockIdx.x*64 + threadIdx.x;
    if (idx < 7*4*64) {
        int lane = idx & 63, kt = (idx>>6)&3, nt = idx>>8;
        int n = nt*16 + (lane&15);
        int kb = kt*32 + (lane>>4)*8;
        unsigned wv[4];
        #pragma unroll
        for (int p = 0; p < 4; ++p) {
            float v0 = (n < H_) ? W1[(kb+2*p  )*H_ + n] : 0.f;
            float v1 = (n < H_) ? W1[(kb+2*p+1)*H_ + n] : 0.f;
            wv[p] = f2bf1(v0) | (f2bf1(v1) << 16);
        }
        W1f[idx] = make_uint4(wv[0],wv[1],wv[2],wv[3]);
    } else {
        int id2 = idx - 7*4*64;              // grid sized so id2 < 4*4*64
        int lane = id2 & 63, kt = (id2>>6)&3, nt = id2>>8;
        int n = nt*16 + (lane&15);
        int kb = kt*32 + (lane>>4)*8;
        unsigned wv[4];
        #pragma unroll
        for (int p = 0; p < 4; ++p) {
            int k0 = kb+2*p, k1 = kb+2*p+1;
            float v0 = (k0 < H_) ? W2[k0*T_ + n] : 0.f;
            float v1 = (k1 < H_) ? W2[k1*T_ + n] : 0.f;
            wv[p] = f2bf1(v0) | (f2bf1(v1) << 16);
        }
        W2f[id2] = make_uint4(wv[0],wv[1],wv[2],wv[3]);
    }
}

// ---------------------------------------------------------------------------
// MLP. ROUND 8 change: em stores go through a per-wave LDS transpose
// (row stride 144 B: 2-way banks = free, 16B-aligned) then coalesced
// dwordx4 global stores — was 16x scalar 2B stores/lane at stride 128B
// (WRITE_SIZE 71 MB vs 33 ideal at r2).
// ---------------------------------------------------------------------------
__global__ __launch_bounds__(256, 4) void mlp_kernel(
    const int* __restrict__ inputs, const float* __restrict__ tbl,
    const float* __restrict__ b1, const float* __restrict__ b2,
    const uint4* __restrict__ W1f, const uint4* __restrict__ W2f,
    unsigned short* __restrict__ em)
{
    __shared__ uint4 sA2[1024];    // 16 KB; per-wave: A2 frags, then out-transpose

    const int tid  = threadIdx.x;
    const int lane = tid & 63;
    const int w    = tid >> 6;
    const int col  = lane & 15;
    const int hi   = lane >> 4;
    const int rowin = hi * 4;      // C/D: col=lane&15, row=(lane>>4)*4+reg (m89)

    const int rg = blockIdx.x*64 + w*16 + col;
    const int i0 = inputs[rg*3+0], i1 = inputs[rg*3+1], i2 = inputs[rg*3+2];
    const float4* r0 = (const float4*)tbl + (size_t)i0*(E_/4);
    const float4* r1 = (const float4*)tbl + (size_t)i1*(E_/4);
    const float4* r2 = (const float4*)tbl + (size_t)i2*(E_/4);

    U16x4 a[4];
    #pragma unroll
    for (int kt = 0; kt < 4; ++kt) {
        int fo = kt*8 + hi*2;
        float4 x0 = r0[fo], y0 = r0[fo+1];
        float4 x1 = r1[fo], y1 = r1[fo+1];
        float4 x2 = r2[fo], y2 = r2[fo+1];
        float v0 = x0.x+x1.x+x2.x, v1 = x0.y+x1.y+x2.y;
        float v2 = x0.z+x1.z+x2.z, v3 = x0.w+x1.w+x2.w;
        float v4 = y0.x+y1.x+y2.x, v5 = y0.y+y1.y+y2.y;
        float v6 = y0.z+y1.z+y2.z, v7 = y0.w+y1.w+y2.w;
        a[kt].u = make_uint4(f2bf1(v0)|(f2bf1(v1)<<16), f2bf1(v2)|(f2bf1(v3)<<16),
                             f2bf1(v4)|(f2bf1(v5)<<16), f2bf1(v6)|(f2bf1(v7)<<16));
    }

    f32x4 acc1[7];
    #pragma unroll
    for (int nt = 0; nt < 7; ++nt) {
        int n = nt*16 + col;
        float bv = (n < H_) ? b1[n] : 0.f;
        f32x4 c; c[0]=bv; c[1]=bv; c[2]=bv; c[3]=bv;
        #pragma unroll
        for (int k = 0; k < 4; ++k) {
            U16x4 bfr; bfr.u = W1f[(nt*4+k)*64 + lane];
            c = __builtin_amdgcn_mfma_f32_16x16x32_bf16(a[k].s, bfr.s, c, 0,0,0);
        }
        acc1[nt] = c;
    }
    #pragma unroll
    for (int nt = 0; nt < 7; ++nt)
        #pragma unroll
        for (int rr = 0; rr < 4; ++rr) {
            float x = acc1[nt][rr];
            acc1[nt][rr] = 1.f - 2.f/(__expf(2.f*x)+1.f);
        }

    if (lane >= 32) sA2[(w*4+3)*64 + lane] = make_uint4(0,0,0,0);
    unsigned short* A2h = (unsigned short*)sA2;
    #pragma unroll
    for (int nt = 0; nt < 7; ++nt)
        #pragma unroll
        for (int rr = 0; rr < 4; ++rr) {
            int k2 = nt*16 + col;
            int kt2 = k2 >> 5, g2 = (k2>>3)&3, i2v = k2&7;
            int u4idx = (w*4 + kt2)*64 + g2*16 + (rowin + rr);
            A2h[u4idx*8 + i2v] = (unsigned short)f2bf1(acc1[nt][rr]);
        }
    __builtin_amdgcn_wave_barrier();

    U16x4 a2[4];
    #pragma unroll
    for (int k = 0; k < 4; ++k) a2[k].u = sA2[(w*4+k)*64 + lane];
    __builtin_amdgcn_wave_barrier();   // a2 loaded; wave's quarter reusable

    // out-transpose buffer: 16 rows x 72 shorts (144 B stride) in wave quarter
    unsigned short* tbuf = (unsigned short*)(sA2 + (size_t)w*256);
    #pragma unroll
    for (int nt2 = 0; nt2 < 4; ++nt2) {
        float bv = b2[nt2*16 + col];
        f32x4 c; c[0]=bv; c[1]=bv; c[2]=bv; c[3]=bv;
        #pragma unroll
        for (int k = 0; k < 4; ++k) {
            U16x4 bfr; bfr.u = W2f[(nt2*4+k)*64 + lane];
            c = __builtin_amdgcn_mfma_f32_16x16x32_bf16(a2[k].s, bfr.s, c, 0,0,0);
        }
        #pragma unroll
        for (int rr = 0; rr < 4; ++rr)
            tbuf[(rowin+rr)*72 + nt2*16 + col] = (unsigned short)f2bf1(c[rr]);
    }
    __builtin_amdgcn_wave_barrier();

    {
        const int rl = lane >> 2;            // local row 0..15
        const int ch = (lane & 3) * 2;       // uint4 chunk pair 0,2,4,6
        const uint4* t4 = (const uint4*)tbuf;
        uint4 u0 = t4[rl*9 + ch];
        uint4 u1 = t4[rl*9 + ch + 1];
        size_t rowg = (size_t)(blockIdx.x*64 + w*16 + rl);
        uint4* dst = (uint4*)(em + rowg*T_);
        dst[ch]   = u0;
        dst[ch+1] = u1;
    }
}

// ---------------------------------------------------------------------------
// CRF scan — EXACT round-4 kernel (measured 164 us). Linear-space recursion,
// LDS broadcast of unscaled a, f32x2 pk-FMA tree, rescale bookkeeping
// off-chain. (Readlane variants r5-r7 all ~264 us: VALU->SGPR->VALU hazard.)
// ---------------------------------------------------------------------------
__global__ __launch_bounds__(64) void crf_kernel(
    const int* __restrict__ inputs, const int* __restrict__ tags,
    const unsigned short* __restrict__ em, const float* __restrict__ start_trans,
    const float* __restrict__ end_trans, const float* __restrict__ trans,
    float* __restrict__ out)
{
    __shared__ unsigned short sem[2][8*T_];   // 2 x 1 KB em staging
    __shared__ float pbuf[T_];

    const int b = blockIdx.x;
    const int j = threadIdx.x;
    const unsigned short* em_b = em + (size_t)b*S_*T_;
    const int* tags_b = tags + b*S_;
    const int* in_b = inputs + (size_t)b*S_*3;

    // mask ballots + numerator
    unsigned long long mball[8];
    float partial = 0.f;
    #pragma unroll
    for (int g = 0; g < 8; ++g) {
        int t = g*64 + j;
        int a0 = in_b[t*3+0], a1 = in_b[t*3+1], a2 = in_b[t*3+2];
        bool mk = ((a0 | a1 | a2) != 0);
        mball[g] = __ballot(mk);
        if (t >= 1 && mk) {
            int tp = tags_b[t-1], tc = tags_b[t];
            partial += trans[tp*T_ + tc] + bf2f(em_b[(size_t)t*T_ + tc]);
        }
    }
    int mcount = 0;
    #pragma unroll
    for (int g = 0; g < 8; ++g) mcount += __popcll(mball[g]);
    mball[0] &= ~1ull;
    #pragma unroll
    for (int off = 32; off >= 1; off >>= 1) partial += __shfl_xor(partial, off, 64);
    const int tag0 = tags_b[0];
    int se = mcount - 1; if (se < 0) se = 0;
    const int last_tag = tags_b[se];
    const float numer = partial + start_trans[tag0] + bf2f(em_b[tag0]) + end_trans[last_tag];

    // E column j as f32x2 pairs (constant over scan)
    f32x2 E2[32];
    #pragma unroll
    for (int i = 0; i < 32; ++i) {
        f32x2 e; e.x = __expf(trans[(2*i)*T_ + j]); e.y = __expf(trans[(2*i+1)*T_ + j]);
        E2[i] = e;
    }

    // init: a = exp(alpha0 - m), ls = m
    float x0v = start_trans[j] + bf2f(em_b[j]);
    float ls = rfl_f(x0v);
    float a = __expf(x0v - ls);

    // group staging: sem[g&1] holds group g; eg[] = exp(em) for current group
    const uint4* em4 = (const uint4*)em_b;
    uint4 gbuf = em4[j];
    ((uint4*)sem[0])[j] = gbuf;
    __builtin_amdgcn_wave_barrier();
    float eg[8];
    #pragma unroll
    for (int c = 0; c < 8; ++c) eg[c] = __expf(bf2f(sem[0][c*T_ + j]));
    gbuf = em4[64 + j];

    for (int g = 0; g < 64; ++g) {
        unsigned short raw16[8];
        if (g < 63) {
            ((uint4*)sem[(g+1)&1])[j] = gbuf;
            __builtin_amdgcn_wave_barrier();
            #pragma unroll
            for (int c = 0; c < 8; ++c) raw16[c] = sem[(g+1)&1][c*T_ + j];
            if (g < 62) gbuf = em4[(g+2)*64 + j];
        }
        const unsigned mg = (unsigned)((mball[g>>3] >> ((g&7)*8)) & 0xFFull);

        #pragma unroll
        for (int c = 0; c < 8; ++c) {
            pbuf[j] = a;                           // broadcast UNSCALED a
            __builtin_amdgcn_wave_barrier();
            float s    = rfl_f(a);                 // overlaps LDS round-trip
            float sinv = __builtin_amdgcn_rcpf(s);
            float logs = __logf(s);                // off-chain (ls accumulator)
            float keep = a * sinv;
            float dmul = eg[c] * sinv;
            const float4* pb4 = (const float4*)pbuf;
            f32x2 ac0={0.f,0.f}, ac1={0.f,0.f}, ac2={0.f,0.f}, ac3={0.f,0.f};
            #pragma unroll
            for (int q = 0; q < 4; ++q) {
                float4 A0 = pb4[4*q+0], A1 = pb4[4*q+1], A2v = pb4[4*q+2], A3 = pb4[4*q+3];
                f32x2 p0; p0.x=A0.x; p0.y=A0.y;  f32x2 p1; p1.x=A0.z; p1.y=A0.w;
                f32x2 p2; p2.x=A1.x; p2.y=A1.y;  f32x2 p3; p3.x=A1.z; p3.y=A1.w;
                f32x2 p4; p4.x=A2v.x;p4.y=A2v.y; f32x2 p5; p5.x=A2v.z;p5.y=A2v.w;
                f32x2 p6; p6.x=A3.x; p6.y=A3.y;  f32x2 p7; p7.x=A3.z; p7.y=A3.w;
                ac0 = p0*E2[8*q+0] + ac0;  ac1 = p1*E2[8*q+1] + ac1;
                ac2 = p2*E2[8*q+2] + ac2;  ac3 = p3*E2[8*q+3] + ac3;
                ac0 = p4*E2[8*q+4] + ac0;  ac1 = p5*E2[8*q+5] + ac1;
                ac2 = p6*E2[8*q+6] + ac2;  ac3 = p7*E2[8*q+7] + ac3;
            }
            f32x2 st = (ac0+ac1)+(ac2+ac3);
            float dot = st.x + st.y;
            float cand = dot * dmul;
            a = ((mg >> c) & 1u) ? cand : keep;
            ls += logs;
            __builtin_amdgcn_wave_barrier();
        }
        if (g < 63) {
            #pragma unroll
            for (int c = 0; c < 8; ++c) eg[c] = __expf(bf2f(raw16[c]));
        }
    }

    // denominator = ls + log(sum_j a_j * exp(end_j))
    float x = a * __expf(end_trans[j]);
    #pragma unroll
    for (int off = 32; off >= 1; off >>= 1) x += __shfl_xor(x, off, 64);
    if (j == 0) out[b] = ls + __logf(x) - numer;
}

// ---------------------------------------------------------------------------
extern "C" void kernel_launch(void* const* d_in, const int* in_sizes, int n_in,
                              void* d_out, int out_size, void* d_ws, size_t ws_size,
                              hipStream_t stream) {
    const int*   inputs      = (const int*)  d_in[0];
    const int*   tags        = (const int*)  d_in[1];
    const float* emb_table   = (const float*)d_in[2];
    const float* W1          = (const float*)d_in[3];
    const float* b1          = (const float*)d_in[4];
    const float* W2          = (const float*)d_in[5];
    const float* b2          = (const float*)d_in[6];
    const float* start_trans = (const float*)d_in[7];
    const float* end_trans   = (const float*)d_in[8];
    const float* transitions = (const float*)d_in[9];
    float* out = (float*)d_out;

    unsigned short* em = (unsigned short*)d_ws;            // 32 MiB bf16
    uint4* W1f = (uint4*)((char*)d_ws + (size_t)BS_*T_*2);
    uint4* W2f = W1f + 7*4*64;

    prep_kernel<<<dim3((7*4*64 + 4*4*64)/64), dim3(64), 0, stream>>>(W1, W2, W1f, W2f);
    mlp_kernel<<<dim3(BS_/64), dim3(256), 0, stream>>>(
        inputs, emb_table, b1, b2, W1f, W2f, em);
    crf_kernel<<<dim3(B_), dim3(64), 0, stream>>>(
        inputs, tags, em, start_trans, end_trans, transitions, out);
}